// Round 1
// 519.495 us; speedup vs baseline: 1.0031x; 1.0031x over previous
//
#include <hip/hip_runtime.h>

// Problem constants: BS=32, SEQ=2048, IN=512, H=256, L=2
#define SEQL 2048
#define BSZ  32
#define HDIM 256
#define MTOT (BSZ*SEQL)          // 65536 rows
#define XXN  ((size_t)MTOT*512)  // xx output elems

typedef short v8s __attribute__((ext_vector_type(8)));
typedef float v4f __attribute__((ext_vector_type(4)));

// f32 -> bf16 RNE via native cast: compiler emits v_cvt_pk_bf16_f32 pairs
// (RNE, bit-identical to the old add-0x7FFF bit-twiddle for normal values).
__device__ __forceinline__ short f2bf(float f) {
  return __builtin_bit_cast(short, (__bf16)f);
}

__device__ __forceinline__ v8s pack8(float4 a, float4 b) {
  v8s r;
  r[0] = f2bf(a.x); r[1] = f2bf(a.y); r[2] = f2bf(a.z); r[3] = f2bf(a.w);
  r[4] = f2bf(b.x); r[5] = f2bf(b.y); r[6] = f2bf(b.z); r[7] = f2bf(b.w);
  return r;
}

// C[m][n] = act( sum_k A[m][k]*W[n][k] + bias[n] ), A row stride sa, W is [256][K],
// C row stride 256. act: 0=none, 1=sigmoid. Tile 128x128, 4 waves of 64x64, bf16 MFMA.
// Round-0 polish rewrite:
//  - cvt_pk conversion (was ~180 VALU instrs/K-step of bit-twiddle -> ~16 cvt_pk)
//  - double-buffered LDS: ONE barrier per K-step (was two)
//  - register prefetch of next fp32 tile issued AFTER the barrier so it overlaps
//    ds_read+MFMA and is consumed (vmcnt drained) BEFORE the next barrier -> the
//    compiler's vmcnt(0)-before-s_barrier drain costs nothing.
__global__ __launch_bounds__(256, 3) void gemm_bias_act(
    const float* __restrict__ A, int sa,
    const float* __restrict__ W, int K,
    const float* __restrict__ bias,
    float* __restrict__ C, int act)
{
  // [2 buf][128 rows][32 k + 8 pad] shorts = 40 KiB total (A+B)
  __shared__ short As[2][128*40];
  __shared__ short Bs[2][128*40];

  int tid  = threadIdx.x;
  int m0   = blockIdx.x * 128;
  int n0   = blockIdx.y * 128;
  int lane = tid & 63;
  int wid  = tid >> 6;
  int wr   = wid >> 1, wc = wid & 1;
  int quad = lane >> 4, r16 = lane & 15;

  int srow = tid >> 1;          // staging row 0..127
  int sseg = (tid & 1) * 16;    // k segment 0 or 16 (floats in global, shorts in LDS)

  v4f acc[4][4];
  #pragma unroll
  for (int i = 0; i < 4; ++i)
    #pragma unroll
    for (int j = 0; j < 4; ++j)
      acc[i][j] = (v4f){0.f, 0.f, 0.f, 0.f};

  const float* aB = A + (long)(m0 + srow)*sa + sseg;
  const float* wB = W + (long)(n0 + srow)*K + sseg;

  // prologue: preload K-step 0 into registers
  float4 aCur[4], bCur[4];
  #pragma unroll
  for (int u = 0; u < 4; ++u) {
    aCur[u] = ((const float4*)aB)[u];
    bCur[u] = ((const float4*)wB)[u];
  }

  for (int kk = 0; kk < K; kk += 32) {
    short* Asb = As[(kk >> 5) & 1];
    short* Bsb = Bs[(kk >> 5) & 1];

    // convert + stage current tile (waits vmcnt for the prefetched regs)
    *(v8s*)&Asb[srow*40 + sseg]     = pack8(aCur[0], aCur[1]);
    *(v8s*)&Asb[srow*40 + sseg + 8] = pack8(aCur[2], aCur[3]);
    *(v8s*)&Bsb[srow*40 + sseg]     = pack8(bCur[0], bCur[1]);
    *(v8s*)&Bsb[srow*40 + sseg + 8] = pack8(bCur[2], bCur[3]);
    __syncthreads();   // vmcnt already 0 here (prefetch consumed above) -> no drain stall
    // WAR safety (1 barrier, 2 buffers): a wave reaching iteration i+2's writes of
    // buf(i) has passed barrier(i+1), and every wave's reads of buf(i) complete
    // (lgkmcnt(0)) before it signals barrier(i+1).

    // prefetch next K-step; in flight across ds_read + MFMA below
    if (kk + 32 < K) {
      const float4* ap = (const float4*)(aB + kk + 32);
      const float4* wp = (const float4*)(wB + kk + 32);
      #pragma unroll
      for (int u = 0; u < 4; ++u) { aCur[u] = ap[u]; bCur[u] = wp[u]; }
    }

    // A-frag: A[m=lane&15][k=quad*8+j]; B-frag: B[k=quad*8+j][n=lane&15] = W[n][k]
    v8s af[4], bfv[4];
    #pragma unroll
    for (int i = 0; i < 4; ++i)
      af[i] = *(const v8s*)&Asb[(wr*64 + i*16 + r16)*40 + quad*8];
    #pragma unroll
    for (int j = 0; j < 4; ++j)
      bfv[j] = *(const v8s*)&Bsb[(wc*64 + j*16 + r16)*40 + quad*8];
    #pragma unroll
    for (int i = 0; i < 4; ++i)
      #pragma unroll
      for (int j = 0; j < 4; ++j)
        acc[i][j] = __builtin_amdgcn_mfma_f32_16x16x32_bf16(af[i], bfv[j], acc[i][j], 0, 0, 0);
  }

  // Epilogue: C/D layout col=lane&15, row=quad*4+reg
  #pragma unroll
  for (int j = 0; j < 4; ++j) {
    int col = n0 + wc*64 + j*16 + r16;
    float bv = bias[col];
    #pragma unroll
    for (int i = 0; i < 4; ++i) {
      int rowb = m0 + wr*64 + i*16 + quad*4;
      #pragma unroll
      for (int r = 0; r < 4; ++r) {
        float v = acc[i][j][r] + bv;
        if (act) {
          float e = __builtin_amdgcn_exp2f(v * -1.4426950408889634f);
          v = __builtin_amdgcn_rcpf(1.f + e);
        }
        C[(long)(rowb + r)*HDIM + col] = v;
      }
    }
  }
}

// Segment-parallel recurrence: h = tanh(x*(g*h + (1-g)*x)).
// Chain per (dir,b,f) split into 8 time-segments of 256 steps; each segment
// starts h=0 with a 64-step warmup (contraction kills the seed error; see
// round-3 journal). 2048 blocks x 64 thr = 8 waves/CU -> latency hidden by
// TLP (rounds 1-2 proved in-wave pipelining can't fix 1-wave/CU stalls).
// Chain: 4 dep ops/step: tanh(p)=1-2*rcp(e^{2p}+1); r:=rcp(exp2(q)+1);
// q_{t+1}=fma(-2K*a', r, K*(a'+b')), K=2*log2e. r=0.5 <=> h=0. No NaN path.
// Stores batched per 16-step chunk (keeps vmcnt ordering clean).
__global__ __launch_bounds__(64) void recur(
    const float* __restrict__ X, int sx, int xoffR,
    const float* __restrict__ G, int sg, int goffR,
    float* __restrict__ Y, float* __restrict__ hout)
{
  const int T = 16;
  const int SEGS = 8;
  const int SEGLEN = SEQL / SEGS;   // 256
  const int WARM = 64;

  int blk = blockIdx.x & 255;
  int seg = blockIdx.x >> 8;        // 0..7
  int fg = blk & 3;
  int b  = (blk >> 2) & 31;
  int d  = blk >> 7;
  int f  = fg*64 + threadIdx.x;

  int u0    = seg*SEGLEN - (seg ? WARM : 0);   // virtual-time start (incl warmup)
  int warmc = seg ? (WARM/T) : 0;              // 4 or 0 warmup chunks
  int nc    = warmc + SEGLEN/T;                // 20 or 16 chunks
  int half  = nc >> 1;

  int stp  = d ? -1 : 1;
  int t0   = d ? (SEQL-1 - u0) : u0;
  int xoff = d ? xoffR : 0;
  int goff = d ? goffR : 0;

  const float* xc = X + (long)(b*SEQL + t0)*sx + xoff + f;
  const float* gc = G + (long)(b*SEQL + t0)*sg + goff + f;
  long xstep = (long)stp * sx;
  long gstep = (long)stp * sg;

  int ty0 = d ? (SEQL-1 - seg*SEGLEN) : seg*SEGLEN;
  float* yp = Y + (long)(b*SEQL + ty0)*512 + d*HDIM + f;
  long ystep = (long)stp * 512;

  const float K   = 2.8853900817779268f;   // 2*log2(e)
  const float mK2 = -5.7707801635558537f;  // -2K

  float Ax[T], Ag[T], Bx[T], Bg[T], hb[T];
  #pragma unroll
  for (int j = 0; j < T; ++j) { Ax[j] = xc[xstep*j]; Ag[j] = gc[gstep*j]; }

  float r = 0.5f;   // encodes h = 0

  auto compute = [&](float* xb, float* gb) {
    #pragma unroll
    for (int j = 0; j < T; ++j) {
      float x = xb[j], g = gb[j];
      float a = x * g;                       // off-chain
      float m = a * mK2;                     // off-chain
      float n = K * fmaf(x, x - a, a);       // off-chain: K*(a + x^2*(1-g))
      float q = fmaf(m, r, n);               // chain 1
      float E = __builtin_amdgcn_exp2f(q);   // chain 2
      r = __builtin_amdgcn_rcpf(E + 1.0f);   // chain 3+4
      hb[j] = fmaf(-2.0f, r, 1.0f);          // off-chain
    }
  };
  auto flush = [&](int c) {
    if (c >= warmc) {                        // wave-uniform
      #pragma unroll
      for (int j = 0; j < T; ++j) yp[ystep*j] = hb[j];
      yp += ystep*T;
    }
  };

  int c = 0;
  for (int it = 0; it < half; ++it) {
    // prefetch chunk c+1 into B (always valid: c+1 <= nc-1)
    const float* xn = xc + xstep*T;
    const float* gn = gc + gstep*T;
    #pragma unroll
    for (int j = 0; j < T; ++j) { Bx[j] = xn[xstep*j]; Bg[j] = gn[gstep*j]; }
    compute(Ax, Ag); flush(c);
    // prefetch chunk c+2 into A (clamped on last iteration)
    bool hv = (c+2 < nc);
    const float* xn2 = hv ? xn + xstep*T : xn;
    const float* gn2 = hv ? gn + gstep*T : gn;
    #pragma unroll
    for (int j = 0; j < T; ++j) { Ax[j] = xn2[xstep*j]; Ag[j] = gn2[gstep*j]; }
    compute(Bx, Bg); flush(c+1);
    xc = xn2; gc = gn2; c += 2;
  }

  if (seg == SEGS-1)
    hout[(size_t)d*BSZ*HDIM + (size_t)b*HDIM + f] = fmaf(-2.0f, r, 1.0f);
}

extern "C" void kernel_launch(void* const* d_in, const int* in_sizes, int n_in,
                              void* d_out, int out_size, void* d_ws, size_t ws_size,
                              hipStream_t stream) {
  const float* x    = (const float*)d_in[0];
  const float* W_fc = (const float*)d_in[1];
  const float* b_fc = (const float*)d_in[2];
  // d_in[3]=W1, d_in[4]=b1: mathematically dead (blending1 == identity)
  const float* W2   = (const float*)d_in[5];
  const float* b2   = (const float*)d_in[6];

  float* out  = (float*)d_out;
  float* bufA = (float*)d_ws;                      // 64 MiB (l0) / 128 MiB (l1 gates)
  float* bufB = bufA + (size_t)MTOT*HDIM;          // 64 MiB
  float* xx   = out;                               // [32][2048][512]
  float* hout = out + XXN;                         // [4][32][256]

  // H0 = x @ W_fc.T + b_fc            -> bufA  [65536][256]
  gemm_bias_act<<<dim3(512,2), 256, 0, stream>>>(x, 512, W_fc, 512, b_fc, bufA, 0);
  // G0 = sigmoid(H0 @ W2_0.T + b2_0)  -> bufB  (rtl gates = time-flip of same)
  gemm_bias_act<<<dim3(512,2), 256, 0, stream>>>(bufA, HDIM, W2, HDIM, b2, bufB, 1);
  // layer 0 recurrence: X=H0 (both halves of xx equal), writes xx into d_out
  recur<<<2048, 64, 0, stream>>>(bufA, HDIM, 0, bufB, HDIM, 0, xx, hout);
  // layer 1 gates, ONE GEMM: xx flat = [131072][256] rows (ltr/rtl halves are
  // alternating rows, same W2_1) -> bufA as [b][t][2][256]
  gemm_bias_act<<<dim3(1024,2), 256, 0, stream>>>(xx, HDIM, W2 + HDIM*HDIM, HDIM, b2 + HDIM, bufA, 1);
  // layer 1 recurrence, in place in d_out; Gl at +0, Gr at +256, stride 512
  recur<<<2048, 64, 0, stream>>>(xx, 512, 256, bufA, 512, 256, xx, hout + 2*BSZ*HDIM);
}